// Round 12
// baseline (263.794 us; speedup 1.0000x reference)
//
#include <hip/hip_runtime.h>

typedef unsigned short u16;
typedef __attribute__((ext_vector_type(8))) __bf16 bf16x8;
typedef __attribute__((ext_vector_type(4))) float f32x4;
typedef __attribute__((ext_vector_type(4))) u16 u16x4;
typedef __attribute__((ext_vector_type(8))) u16 u16x8;

constexpr int S = 2048;
constexpr int H = 2048;
constexpr int NH = 16;
constexpr int HD = 128;
constexpr int M = 4096;   // B*S
constexpr float SCALE = 0.08838834764831845f;  // 1/sqrt(128)

__device__ __forceinline__ u16 f2bf(float f) {
  union { float f; unsigned u; } v; v.f = f;
  unsigned r = v.u + 0x7fffu + ((v.u >> 16) & 1u);  // RNE
  return (u16)(r >> 16);
}
__device__ __forceinline__ float bf2f(u16 u) {
  union { unsigned u; float f; } v; v.u = ((unsigned)u) << 16;
  return v.f;
}
__device__ __forceinline__ unsigned cvt_pk_bf16(float lo, float hi) {
  unsigned r;
  asm("v_cvt_pk_bf16_f32 %0, %1, %2" : "=v"(r) : "v"(lo), "v"(hi));
  return r;
}
__device__ __forceinline__ float fract_f(float x) {
  float o; asm("v_fract_f32 %0, %1" : "=v"(o) : "v"(x)); return o;
}
__device__ __forceinline__ float sin_rev(float x) {  // x in revolutions, [0,1)
  float o; asm("v_sin_f32 %0, %1" : "=v"(o) : "v"(x)); return o;
}
__device__ __forceinline__ float cos_rev(float x) {
  float o; asm("v_cos_f32 %0, %1" : "=v"(o) : "v"(x)); return o;
}
__device__ __forceinline__ f32x4 MFMA16(bf16x8 a, bf16x8 b, f32x4 c) {
  return __builtin_amdgcn_mfma_f32_16x16x32_bf16(a, b, c, 0, 0, 0);
}

// async global->LDS, 16 bytes per lane. LDS dest must be wave-uniform base + lane*16.
__device__ __forceinline__ void gld16(const u16* g, u16* l) {
  __builtin_amdgcn_global_load_lds(
      (const __attribute__((address_space(1))) void*)g,
      (__attribute__((address_space(3))) void*)l, 16, 0, 0);
}

#define SBAR  { __builtin_amdgcn_sched_barrier(0); __builtin_amdgcn_s_barrier(); __builtin_amdgcn_sched_barrier(0); }
#define LGKM0 { asm volatile("s_waitcnt lgkmcnt(0)" ::: "memory"); __builtin_amdgcn_sched_barrier(0); }

// ---------------- fused prep: x cast | 4 weight casts (Q/K pair-interleaved) | bias ----------------
// Q/K weight-row permutation: head-dim d<64 -> 2d, d>=64 -> 2(d-64)+1. RoPE partners (d,d+64)
// become adjacent output columns -> GEMM-epilogue RoPE needs only __shfl_xor(x,1).
// Q,K share the permutation => QK^T invariant. V and Wo untouched.
__global__ __launch_bounds__(256) void prep_kernel(const float* __restrict__ x,
                                                   const float* __restrict__ wq,
                                                   const float* __restrict__ wk,
                                                   const float* __restrict__ wv,
                                                   const float* __restrict__ wo,
                                                   const float* __restrict__ bq,
                                                   const float* __restrict__ bk,
                                                   const float* __restrict__ bv,
                                                   u16* __restrict__ xb,
                                                   u16* __restrict__ wqkvb,
                                                   u16* __restrict__ wob,
                                                   float* __restrict__ bqkv) {
  const int NX = (M * H) / 1024;       // 8192 blocks for x
  const int NW = (H * H) / 1024;       // 4096 blocks per weight
  int bid = blockIdx.x;
  if (bid < NX) {                      // x cast, straight
    int i = (bid * 256 + threadIdx.x) * 4;
    float4 v = *(const float4*)(x + i);
    u16x4 o;
    o[0] = f2bf(v.x); o[1] = f2bf(v.y); o[2] = f2bf(v.z); o[3] = f2bf(v.w);
    *(u16x4*)(xb + i) = o;
    return;
  }
  bid -= NX;
  if (bid < 4 * NW) {                  // weight casts
    const int z = bid / NW, lb = bid % NW;
    const float* in;
    u16* out;
    switch (z) {
      case 0: in = wq; out = wqkvb; break;
      case 1: in = wk; out = wqkvb + (size_t)H * H; break;
      case 2: in = wv; out = wqkvb + 2ull * H * H; break;
      default: in = wo; out = wob; break;
    }
    int i = (lb * 256 + threadIdx.x) * 4;        // OUTPUT flat index
    int ro = i >> 11, cb = i & 2047;
    int rin = ro;
    if (z < 2) {                                  // gather from permuted source row
      int nd = ro & 127;
      int od = (nd & 1) ? (nd >> 1) + 64 : (nd >> 1);
      rin = (ro & ~127) | od;
    }
    float4 v = *(const float4*)(in + (size_t)rin * H + cb);
    u16x4 o;
    o[0] = f2bf(v.x); o[1] = f2bf(v.y); o[2] = f2bf(v.z); o[3] = f2bf(v.w);
    *(u16x4*)(out + i) = o;
    return;
  }
  bid -= 4 * NW;                       // bias concat (Q/K permuted): 24 blocks
  int i = bid * 256 + threadIdx.x;     // 0..6143
  if (i < 4096) {
    const float* src = (i < 2048) ? bq : bk;
    int base = i & 2047;
    int nd = base & 127;
    int od = (nd & 1) ? (nd >> 1) + 64 : (nd >> 1);
    bqkv[i] = src[(base & ~127) | od];
  } else {
    bqkv[i] = bv[i & 2047];
  }
}

// ================= R5-proven 256(M) x NW*64(N) 8-phase GEMM =================
// C[m,n] = sum_k A[m,k]*W[n,k] + bias[n]; K=2048, BK=64 (32 K-tiles, 16 iters x 2).
// 8 waves (2M x 4N), per-wave 128 x NW*16. LDS: A 2x[256][64], B 2x[NW*64][64].
// Chunk-XOR swizzle (source-swizzled stage, same involution on ds_read) -> 0 conflicts.
// Stage ledger: ph1 A1h0, ph2 A1h1, ph4 B0<-u+2 + GATE; ph5/6 A0 halves, ph8 B1<-u+3 + GATE.
// EMODE 0: fp32 out. EMODE 3: fused QKV (Q/K: bias + shfl-pair RoPE w/ on-the-fly trig;
// V: bias + transpose). No table: cos/sin via v_exp/v_fract/v_sin/v_cos (revolutions).
template<int NW, int EMODE>
__device__ __forceinline__ void gemm_body(const u16* __restrict__ A,
                                          const u16* __restrict__ Bw,
                                          const float* __restrict__ bias,
                                          void* __restrict__ out0, void* __restrict__ out1,
                                          void* __restrict__ out2,
                                          int brow, int bcol,
                                          u16* AsL, u16* BsL) {
  const int t = threadIdx.x;
  const int w = t >> 6, l = t & 63;
  const int wr = w >> 2, wc = w & 3;
  const int lr = l & 15, lg = l >> 4;
  const int swz = lr & 7;

  f32x4 acc[8][NW] = {};
  bf16x8 af[4], b0[NW], b1[NW];

  const int sr = t >> 3, sj = t & 7;   // stage row (0..63) / chunk (0..7)

  auto STAGE_A = [&](int BUF, int HALF, int TILE) {
    u16* d = AsL + BUF * (256 * 64) + HALF * (128 * 64);
    const u16* sp = A + (size_t)(brow + HALF * 128) * H + TILE * 64;
    gld16(sp + (size_t)sr * H        + ((sj ^ (sr & 7)) * 8), d + t * 8);
    gld16(sp + (size_t)(64 + sr) * H + ((sj ^ (sr & 7)) * 8), d + (512 + t) * 8);
  };
  auto STAGE_B = [&](int BUF, int TILE) {
    u16* d = BsL + BUF * (NW * 64 * 64);
    const u16* sp = Bw + (size_t)bcol * H + TILE * 64;
    #pragma unroll
    for (int i = 0; i < NW; ++i)
      gld16(sp + (size_t)(i * 64 + sr) * H + ((sj ^ (sr & 7)) * 8),
            d + (i * 512 + t) * 8);
  };
  auto LDA = [&](int BUF, int KH, int MB) {
    const u16* base = AsL + BUF * (256 * 64) + (wr * 128 + MB * 16 + lr) * 64;
    #pragma unroll
    for (int i = 0; i < 4; ++i)
      af[i] = *(const bf16x8*)(base + i * (16 * 64) + (((KH * 4 + lg) ^ swz) * 8));
  };
  auto LDB = [&](int BUF, int KH, bf16x8* bb) {
    const u16* base = BsL + BUF * (NW * 64 * 64) + (wc * (NW * 16) + lr) * 64;
    #pragma unroll
    for (int n = 0; n < NW; ++n)
      bb[n] = *(const bf16x8*)(base + n * (16 * 64) + (((KH * 4 + lg) ^ swz) * 8));
  };
  auto MM = [&](int MB, bf16x8* bb) {
    __builtin_amdgcn_s_setprio(1);
    #pragma unroll
    for (int i = 0; i < 4; ++i)
      #pragma unroll
      for (int n = 0; n < NW; ++n)
        acc[MB + i][n] = MFMA16(af[i], bb[n], acc[MB + i][n]);
    __builtin_amdgcn_s_setprio(0);
  };
  auto GATE = [&]() {
    if constexpr (NW == 3) { asm volatile("s_waitcnt vmcnt(3)" ::: "memory"); }
    else                   { asm volatile("s_waitcnt vmcnt(2)" ::: "memory"); }
  };

  // prologue: A0<-t0, B0<-t0, B1<-t1; retire all but B1
  STAGE_A(0, 0, 0); STAGE_A(0, 1, 0);
  STAGE_B(0, 0);
  STAGE_B(1, 1);
  GATE();
  SBAR;

  for (int J = 0; J < 16; ++J) {
    const int u = 2 * J;
    const bool more = (J < 15);
    // ---- tile u (buf0) ----
    LDA(0, 0, 0); LDB(0, 0, b0);
    STAGE_A(1, 0, u + 1);
    SBAR; LGKM0; MM(0, b0); SBAR;
    LDA(0, 0, 4);
    STAGE_A(1, 1, u + 1);
    SBAR; LGKM0; MM(4, b0); SBAR;
    LDA(0, 1, 0); LDB(0, 1, b1);
    SBAR; LGKM0; MM(0, b1); SBAR;
    LDA(0, 1, 4);
    if (more) STAGE_B(0, u + 2);
    SBAR; LGKM0; MM(4, b1);
    if (more) { GATE(); } else { asm volatile("s_waitcnt vmcnt(0)" ::: "memory"); }
    SBAR;
    // ---- tile u+1 (buf1) ----
    LDA(1, 0, 0); LDB(1, 0, b0);
    if (more) STAGE_A(0, 0, u + 2);
    SBAR; LGKM0; MM(0, b0); SBAR;
    LDA(1, 0, 4);
    if (more) STAGE_A(0, 1, u + 2);
    SBAR; LGKM0; MM(4, b0); SBAR;
    LDA(1, 1, 0); LDB(1, 1, b1);
    SBAR; LGKM0; MM(0, b1); SBAR;
    LDA(1, 1, 4);
    if (more) STAGE_B(1, u + 3);
    SBAR; LGKM0; MM(4, b1);
    if (more) { GATE(); SBAR; }
  }

  // ---- epilogue ----
  // per-lane RoPE frequency (revolutions) for each n: d = (col&127)>>1, shared by lane pairs
  float frv[NW];
  if constexpr (EMODE == 3) {
    #pragma unroll
    for (int n = 0; n < NW; ++n) {
      const int col = ((bcol & 2047) + wc * (NW * 16) + n * 16 + lr);
      const int d = (col & 127) >> 1;
      // 10000^(-d/64) / (2*pi), computed as exp2(-d * log2(10000)/64) * (1/2pi)
      frv[n] = __builtin_amdgcn_exp2f(-(float)d * 0.20762050593f) * 0.15915494309f;
    }
  }
  #pragma unroll
  for (int m = 0; m < 8; ++m) {
    const int row0 = brow + wr * 128 + m * 16 + lg * 4;
    #pragma unroll
    for (int n = 0; n < NW; ++n) {
      const int gcol0 = bcol + wc * (NW * 16) + n * 16;
      const float bv2 = bias[gcol0 + lr];
      if constexpr (EMODE == 0) {
        float* C = (float*)out0;
        #pragma unroll
        for (int r = 0; r < 4; ++r)
          C[(size_t)(row0 + r) * H + gcol0 + lr] = acc[m][n][r] + bv2;
      } else {
        const int sel = gcol0 >> 11;           // wave-uniform (16-col frag never crosses 2048)
        const int col = (gcol0 & 2047) + lr;
        if (sel < 2) {
          // Q/K: bias + RoPE via shfl pair-exchange + on-the-fly trig, + bf16
          u16* Cq = sel ? (u16*)out1 : (u16*)out0;
          const float scl = sel ? 1.f : SCALE;
          #pragma unroll
          for (int r = 0; r < 4; ++r) {
            const int row = row0 + r;
            const float sv = (float)(row & (S - 1));
            float xv = acc[m][n][r] + bv2;
            float pr = __shfl_xor(xv, 1);      // partner: other half of the RoPE pair
            float ang = fract_f(sv * frv[n]);  // revolutions in [0,1)
            float cs = cos_rev(ang), sn = sin_rev(ang);
            float o = (lr & 1) ? (xv * cs + pr * sn)
                               : (xv * cs - pr * sn);
            Cq[(size_t)row * H + col] = f2bf(o * scl);
          }
        } else {
          // V: bias + transposed store Vt[((b*16+h)*128+d)*S + s]
          const int hh = col >> 7, d = col & 127;
          const int b = row0 >> 11, s0 = row0 & (S - 1);
          u16x4 pk;
          #pragma unroll
          for (int r = 0; r < 4; ++r) pk[r] = f2bf(acc[m][n][r] + bv2);
          *(u16x4*)((u16*)out2 + ((size_t)((b * 16 + hh) * 128 + d)) * S + s0) = pk;
        }
      }
    }
  }
}

// fused QKV: M=4096 x N=6144, 256x192 tiles -> 16x32 = 512 blocks (2 exact rounds).
__global__ __launch_bounds__(512, 2) void gemm_qkv8(const u16* __restrict__ xb,
                                                    const u16* __restrict__ wqkv,
                                                    const float* __restrict__ bqkv,
                                                    u16* Qb, u16* Kb, u16* Vt) {
  __shared__ u16 AsL[2 * 256 * 64];   // 64 KiB
  __shared__ u16 BsL[2 * 192 * 64];   // 48 KiB
  const int id = blockIdx.x;
  const int xcd = id & 7, sid = id >> 3;
  const int bx = xcd * 4 + (sid & 3), by = sid >> 2;
  gemm_body<3, 3>(xb, wqkv, bqkv, Qb, Kb, Vt, by * 256, bx * 192, AsL, BsL);
}

// out-proj: M=4096 x N=2048, 256x128 tiles -> 16x16 = 256 blocks (1 exact round).
__global__ __launch_bounds__(512, 2) void gemm_o8(const u16* __restrict__ A,
                                                  const u16* __restrict__ W,
                                                  const float* __restrict__ bias,
                                                  float* __restrict__ C) {
  __shared__ u16 AsL[2 * 256 * 64];   // 64 KiB
  __shared__ u16 BsL[2 * 128 * 64];   // 32 KiB
  const int id = blockIdx.x;
  const int xcd = id & 7, sid = id >> 3;
  const int bx = xcd * 2 + (sid & 1), by = sid >> 1;
  gemm_body<2, 0>(A, W, bias, C, nullptr, nullptr, by * 256, bx * 128, AsL, BsL);
}

// ---------------- causal flash attention (unchanged; Q/K permutation is transparent) ----------------
__global__ __launch_bounds__(256) void attn_fwd(const u16* __restrict__ Q,
                                                const u16* __restrict__ Kx,
                                                const u16* __restrict__ Vt,
                                                u16* __restrict__ O) {
  const int id = blockIdx.x;
  const int xcd = id & 7, slot = id >> 3;
  const int bh = (slot >> 4) * 8 + xcd;    // 0..31
  const int pid = slot & 15;               // 0..15
  const int b = bh >> 4, h = bh & 15;
  const int t = threadIdx.x, w = t >> 6, l = t & 63;
  const int lr = l & 15, lg = l >> 4;
  const int swz = lr & 7;

  __shared__ u16 Ks[2][64 * 128];
  __shared__ u16 Vs[2][128 * 64];
  __shared__ u16 P_lds[4][16 * 64];
  u16* pw = &P_lds[w][0];

  const u16* kbase = Kx + (size_t)(b * S) * H + h * HD;
  const u16* vbase = Vt + (size_t)bh * HD * S;

  auto stageK = [&](int bf, int k0) {
    #pragma unroll
    for (int it = 0; it < 4; ++it) {
      int c = it * 256 + t;
      int row = c >> 4, j = c & 15;
      gld16(kbase + (size_t)(k0 + row) * H + ((j ^ (row & 7)) * 8), &Ks[bf][0] + c * 8);
    }
  };
  auto stageV = [&](int bf, int k0) {
    #pragma unroll
    for (int it = 0; it < 4; ++it) {
      int c = it * 256 + t;
      int row = c >> 3, j = c & 7;
      gld16(vbase + (size_t)row * S + k0 + ((j ^ (row & 7)) * 8), &Vs[bf][0] + c * 8);
    }
  };

  int cur = 0;
  for (int qi = 0; qi < 2; ++qi) {
    const int qt = qi ? pid : (31 - pid);
    const int q0 = qt * 64 + w * 16;

    bf16x8 qa[4];
    const u16* qbase = Q + (size_t)(b * S + q0 + lr) * H + h * HD;
    #pragma unroll
    for (int ks = 0; ks < 4; ++ks)
      qa[ks] = *(const bf16x8*)(qbase + ks * 32 + lg * 8);

    f32x4 acc[8] = {};
    float mrun[4], lrun[4];
    #pragma unroll
    for (int r = 0; r < 4; ++r) { mrun[r] = -1e30f; lrun[r] = 0.f; }

    __syncthreads();
    stageK(cur, 0);
    stageV(cur, 0);
    __syncthreads();

    for (int kt = 0; kt <= qt; ++kt) {
      if (kt < qt) {
        stageK(cur ^ 1, (kt + 1) * 64);
        stageV(cur ^ 1, (kt + 1) * 64);
      }
      const u16* kl = &Ks[cur][0];
      const u16* vl = &Vs[cur][0];

      f32x4 sc[4] = {};
      __builtin_amdgcn_s_setprio(1);
      #pragma unroll
      for (int ks = 0; ks < 4; ++ks) {
        #pragma unroll
        for (int f = 0; f < 4; ++f) {
          bf16x8 kf = *(const bf16x8*)(kl + (f * 16 + lr) * 128 + (((ks * 4 + lg) ^ swz) * 8));
          sc[f] = __builtin_amdgcn_mfma_f32_16x16x32_bf16(qa[ks], kf, sc[f], 0, 0, 0);
        }
      }
      __builtin_amdgcn_s_setprio(0);
      const bool diag = (kt == qt);
      float p[4][4];
      #pragma unroll
      for (int f = 0; f < 4; ++f)
        #pragma unroll
        for (int r = 0; r < 4; ++r) {
          float v = sc[f][r];
          if (diag && (f * 16 + lr > w * 16 + lg * 4 + r)) v = -1e30f;
          p[f][r] = v;
        }
      float mx[4];
      #pragma unroll
      for (int r = 0; r < 4; ++r) {
        float m0 = fmaxf(fmaxf(p[0][r], p[1][r]), fmaxf(p[2][r], p[3][r]));
        m0 = fmaxf(m0, __shfl_xor(m0, 1));
        m0 = fmaxf(m0, __shfl_xor(m0, 2));
        m0 = fmaxf(m0, __shfl_xor(m0, 4));
        m0 = fmaxf(m0, __shfl_xor(m0, 8));
        mx[r] = m0;
      }
      bool grow = (mx[0] > mrun[0] + 8.f) || (mx[1] > mrun[1] + 8.f) ||
                  (mx[2] > mrun[2] + 8.f) || (mx[3] > mrun[3] + 8.f);
      if (__any(grow)) {
        float resc[4];
        #pragma unroll
        for (int r = 0; r < 4; ++r) {
          float mnew = fmaxf(mrun[r], mx[r]);
          resc[r] = __expf(mrun[r] - mnew);
          mrun[r] = mnew;
          lrun[r] *= resc[r];
        }
        #pragma unroll
        for (int fd = 0; fd < 8; ++fd) {
          f32x4 a = acc[fd];
          a[0] *= resc[0]; a[1] *= resc[1]; a[2] *= resc[2]; a[3] *= resc[3];
          acc[fd] = a;
        }
      }
      #pragma unroll
      for (int r = 0; r < 4; ++r) {
        float sum = 0.f;
        #pragma unroll
        for (int f = 0; f < 4; ++f) {
          float e = __expf(p[f][r] - mrun[r]);
          p[f][r] = e;
          sum += e;
        }
        sum += __shfl_xor(sum, 1);
        sum += __shfl_xor(sum, 2);
        sum += __shfl_xor(sum, 4);
        sum += __shfl_xor(sum, 8);
        lrun[r] += sum;
      }
      {
        const int r0 = lg * 4;
        #pragma unroll
        for (int f = 0; f < 4; ++f) {
          const int col = f * 16 + lr;
          unsigned w01 = cvt_pk_bf16(p[f][0], p[f][1]);
          unsigned w23 = cvt_pk_bf16(p[f][2], p[f][3]);
          pw[(r0 + 0) * 64 + (col ^ (((r0 + 0) & 7) << 3))] = (u16)(w01 & 0xffffu);
          pw[(r0 + 1) * 64 + (col ^ (((r0 + 1) & 7) << 3))] = (u16)(w01 >> 16);
          pw[(r0 + 2) * 64 + (col ^ (((r0 + 2) & 7) << 3))] = (u16)(w23 & 0xffffu);
          pw[(r0 + 3) * 64 + (col ^ (((r0 + 3) & 7) << 3))] = (u16)(w23 >> 16);
        }
      }
      __builtin_amdgcn_s_setprio(1);
      #pragma unroll
      for (int ks = 0; ks < 2; ++ks) {
        int col0 = ks * 32 + lg * 8;
        bf16x8 pa = *(const bf16x8*)(pw + lr * 64 + (col0 ^ (swz << 3)));
        #pragma unroll
        for (int fd = 0; fd < 8; ++fd) {
          bf16x8 vb = *(const bf16x8*)(vl + (fd * 16 + lr) * 64 + (((ks * 4 + lg) ^ swz) * 8));
          acc[fd] = __builtin_amdgcn_mfma_f32_16x16x32_bf16(pa, vb, acc[fd], 0, 0, 0);
        }
      }
      __builtin_amdgcn_s_setprio(0);
      __syncthreads();
      cur ^= 1;
    }

    u16* ob = O + (size_t)(b * S + q0 + lg * 4) * H + h * HD;
    #pragma unroll
    for (int r = 0; r < 4; ++r) {
      float inv = 1.f / lrun[r];
      #pragma unroll
      for (int fd = 0; fd < 8; ++fd)
        ob[(size_t)r * H + fd * 16 + lr] = f2bf(acc[fd][r] * inv);
    }
  }
}

// ---------------- launch ----------------
extern "C" void kernel_launch(void* const* d_in, const int* in_sizes, int n_in,
                              void* d_out, int out_size, void* d_ws, size_t ws_size,
                              hipStream_t stream) {
  const float* x  = (const float*)d_in[0];
  const float* wq = (const float*)d_in[1];
  const float* bq = (const float*)d_in[2];
  const float* wk = (const float*)d_in[3];
  const float* bk = (const float*)d_in[4];
  const float* wv = (const float*)d_in[5];
  const float* bv = (const float*)d_in[6];
  const float* wo = (const float*)d_in[7];
  const float* bo = (const float*)d_in[8];

  char* ws = (char*)d_ws;
  u16*   xb    = (u16*)(ws);                      // 16 MiB  [M][H] bf16
  u16*   wqkvb = (u16*)(ws + (16ull << 20));      // 24 MiB  [6144][2048] (Wq|Wk|Wv, Q/K rows permuted)
  u16*   wob   = (u16*)(ws + (40ull << 20));      //  8 MiB
  u16*   Qb    = (u16*)(ws + (48ull << 20));      // 16 MiB (pair-interleaved layout)
  u16*   Kb    = (u16*)(ws + (64ull << 20));      // 16 MiB (pair-interleaved layout)
  u16*   Vt    = (u16*)(ws + (80ull << 20));      // 16 MiB [bh][d][s]
  u16*   Ob    = (u16*)(ws + (96ull << 20));      // 16 MiB
  float* bqkv  = (float*)(ws + (112ull << 20));   // 24 KiB [6144] (Q/K permuted)

  const int NPREP = (M * H) / 1024 + 4 * (H * H) / 1024 + 24;
  prep_kernel<<<NPREP, 256, 0, stream>>>(x, wq, wk, wv, wo, bq, bk, bv,
                                         xb, wqkvb, wob, bqkv);

  gemm_qkv8<<<512, 512, 0, stream>>>(xb, wqkvb, bqkv, Qb, Kb, Vt);

  attn_fwd<<<512, 256, 0, stream>>>(Qb, Kb, Vt, Ob);

  gemm_o8<<<256, 512, 0, stream>>>(Ob, wob, bo, (float*)d_out);
}